// Round 6
// baseline (377.852 us; speedup 1.0000x reference)
//
#include <hip/hip_runtime.h>

#define KDIM 32
#define EPSC 1e-6f
#define NBLK 1024
#define NTHR 256

__device__ __forceinline__ void grid_barrier(int* cnt, int target) {
    __syncthreads();
    if (threadIdx.x == 0) {
        __threadfence();                       // release all prior writes
        atomicAdd(cnt, 1);                     // device-scope
        while (__hip_atomic_load(cnt, __ATOMIC_ACQUIRE, __HIP_MEMORY_SCOPE_AGENT) < target)
            __builtin_amdgcn_s_sleep(4);
        __threadfence();                       // acquire
    }
    __syncthreads();
}

// Single persistent kernel: P1 (M/S atomics) -> bar -> P2 (AZC+X) -> bar ->
// P3 (pairwise tiles + edges, grid-stride) -> ticket -> last block writes out.
__global__ __launch_bounds__(NTHR, 4) void mega(
    const float* __restrict__ beta, const float* __restrict__ gamma,
    const float* __restrict__ Amat,
    const float* __restrict__ Z_i, const float* __restrict__ Z_j,
    const float* __restrict__ Gate,
    const int* __restrict__ si, const int* __restrict__ sj,
    const int* __restrict__ sei, const int* __restrict__ sej,
    float* __restrict__ Macc, float* __restrict__ Sacc,
    int* __restrict__ cnt, float* __restrict__ slots,
    float* __restrict__ Xi_all, float* __restrict__ Xj_all,
    int n_i, int n_j, int m_i, int m_j, int m, int E, float* __restrict__ out)
{
    __shared__ __align__(16) float smemf[4360];
    int tid = threadIdx.x;
    int bid = blockIdx.x;

    // ================= P1: gather + inline softmax + M/S atomic partials =================
    {
        float* Zl   = smemf;                 // [32][33]
        float* Gl   = smemf + 1056;          // [32][33]
        int*   nodeL = (int*)(smemf + 2112); // [32]
        float* cmax = smemf + 2144;          // [32]
        float* cinv = smemf + 2176;          // [32]
        int q = tid & 31, pp = tid >> 5;     // pp in 0..7
        int nblkA = (m + 31) >> 5;
        for (int chunk = bid; chunk < nblkA; chunk += NBLK) {
            __syncthreads();
            if (tid < 32) {
                int mi = chunk * 32 + tid;
                nodeL[tid] = (mi < m) ? ((mi < m_i) ? si[mi] : sj[mi - m_i]) : -1;
            }
            __syncthreads();
            int mi_q = chunk * 32 + q;
            int nq = nodeL[q];
            const float* Zr_q = (mi_q < m_i) ? Z_i : Z_j;
            int n_q = (mi_q < m_i) ? n_i : n_j;
            #pragma unroll
            for (int r = 0; r < 4; r++) {
                int p = r * 8 + pp;
                Zl[p * 33 + q] = (nq >= 0) ? Zr_q[p * n_q + nq] : 0.f;
            }
            __syncthreads();
            if (tid < 32) {   // per-column softmax stats
                float mx = -1e30f;
                #pragma unroll
                for (int rr = 0; rr < 32; rr++) mx = fmaxf(mx, Zl[rr * 33 + tid]);
                float s = 0.f;
                #pragma unroll
                for (int rr = 0; rr < 32; rr++) s += __expf(Zl[rr * 33 + tid] - mx);
                cmax[tid] = mx; cinv[tid] = 1.f / s;
            }
            __syncthreads();
            #pragma unroll
            for (int r = 0; r < 4; r++) {     // in-place softmax (own cell)
                int p = r * 8 + pp;
                float v = Zl[p * 33 + q];
                Zl[p * 33 + q] = (nq >= 0) ? __expf(v - cmax[q]) * cinv[q] : 0.f;
            }
            __syncthreads();
            #pragma unroll
            for (int r = 0; r < 4; r++) {     // Gl[s][q] = zsoft[q][s] * sigmoid(Gate[node_s][q])
                int p = r * 8 + pp;
                int np_ = nodeL[p];
                float gv = 0.f;
                if (np_ >= 0) {
                    float g = 1.f / (1.f + __expf(-Gate[(size_t)np_ * KDIM + q]));
                    gv = Zl[q * 33 + p] * g;  // raw node id for Gate — faithful to reference
                }
                Gl[p * 33 + q] = gv;
            }
            __syncthreads();
            #pragma unroll
            for (int r = 0; r < 4; r++) {
                int p = r * 8 + pp;
                float acc = 0.f;
                #pragma unroll
                for (int s = 0; s < 32; s++) acc = fmaf(Zl[p * 33 + s], Gl[s * 33 + q], acc);
                atomicAdd(&Macc[p * 32 + q], acc);
            }
            if (tid < 32) {
                float ss = 0.f;
                #pragma unroll
                for (int s = 0; s < 32; s++) ss += Gl[s * 33 + tid];
                atomicAdd(&Sacc[tid], ss);
            }
        }
    }
    grid_barrier(&cnt[0], NBLK);

    // ================= P2: AZC in LDS (redundant per active block) + X_all =================
    {
        float* Cn = smemf;          // [32][33]
        float* Al = smemf + 1056;   // [32][32]
        float* Ss = smemf + 2080;   // [32]
        int nTot = n_i + n_j;
        int nXchunks = (nTot + NTHR - 1) / NTHR;
        if (bid < nXchunks) {
            if (tid < 32) Ss[tid] = 1.f / Sacc[tid];
            for (int idx = tid; idx < 1024; idx += NTHR)
                Cn[(idx >> 5) * 33 + (idx & 31)] = Macc[idx];
            __syncthreads();
            for (int idx = tid; idx < 1024; idx += NTHR)
                Cn[(idx >> 5) * 33 + (idx & 31)] *= Ss[idx & 31];
            __syncthreads();
            for (int idx = tid; idx < 1024; idx += NTHR) {
                int d = idx >> 5, qq = idx & 31;
                float s = 0.f;
                #pragma unroll
                for (int j = 0; j < 32; j++) s = fmaf(Amat[d * 32 + j], Cn[j * 33 + qq], s);
                Al[d * 32 + qq] = s;
            }
            __syncthreads();
            int node = bid * NTHR + tid;
            if (node < nTot) {
                const float* Zr; float* X; int n, c;
                if (node < n_i) { Zr = Z_i; X = Xi_all; n = n_i; c = node; }
                else            { Zr = Z_j; X = Xj_all; n = n_j; c = node - n_i; }
                float z[32]; float mx = -1e30f;
                #pragma unroll
                for (int p = 0; p < 32; p++) { z[p] = Zr[p * n + c]; mx = fmaxf(mx, z[p]); }
                float ssum = 0.f;
                #pragma unroll
                for (int p = 0; p < 32; p++) { z[p] = __expf(z[p] - mx); ssum += z[p]; }
                float inv = 1.f / ssum;
                #pragma unroll
                for (int dd = 0; dd < 32; dd++) {
                    float x = 0.f;
                    #pragma unroll
                    for (int p = 0; p < 32; p++) x = fmaf(Al[dd * 32 + p], z[p], x);
                    X[(size_t)c * 32 + dd] = x * inv;   // softmax scale applied once (linear)
                }
            }
        }
    }
    grid_barrier(&cnt[1], NBLK);

    // ================= P3: pairwise tiles + edges (grid-stride) + final =================
    {
        float* XiL = smemf;                  // [64][33]
        float* XjL = smemf + 2112;           // [64][33]
        float* bl  = smemf + 4224;           // [64]
        float* gl  = smemf + 4288;           // [64]
        float* wsum = smemf + 4352;          // [4]
        int* lastFlag = (int*)(smemf + 4356);
        int nbi = (m_i + 63) >> 6, nbj = (m_j + 63) >> 6;
        int npair = nbi * nbj;
        int nedge = (E + NTHR - 1) / NTHR;
        int ntask = npair + nedge;
        float part = 0.f;
        for (int task = bid; task < ntask; task += NBLK) {
            if (task < npair) {
                __syncthreads();   // protect LDS reuse (prev iter / P2)
                int i0 = (task / nbj) * 64, j0 = (task % nbj) * 64;
                #pragma unroll
                for (int l = 0; l < 8; l++) {
                    int idx = tid + l * 256;
                    int row = idx >> 5, dd = idx & 31;
                    int gi = i0 + row;
                    XiL[row * 33 + dd] = (gi < m_i) ? Xi_all[(size_t)si[gi] * 32 + dd] : 0.f;
                    int gj = j0 + row;
                    XjL[row * 33 + dd] = (gj < m_j) ? Xj_all[(size_t)sj[gj] * 32 + dd] : 0.f;
                }
                if (tid < 64) {
                    bl[tid] = (i0 + tid < m_i) ? beta[si[i0 + tid]] : 0.f;
                    gl[tid] = (j0 + tid < m_j) ? gamma[sj[j0 + tid]] : 0.f;
                }
                __syncthreads();
                int ti = tid >> 4, tj = tid & 15;
                float f[4][4] = {};
                #pragma unroll 4
                for (int dd = 0; dd < 32; dd++) {
                    float a0 = XiL[(ti * 4 + 0) * 33 + dd] + EPSC;
                    float a1 = XiL[(ti * 4 + 1) * 33 + dd] + EPSC;
                    float a2 = XiL[(ti * 4 + 2) * 33 + dd] + EPSC;
                    float a3 = XiL[(ti * 4 + 3) * 33 + dd] + EPSC;
                    float b0 = XjL[(tj * 4 + 0) * 33 + dd];
                    float b1 = XjL[(tj * 4 + 1) * 33 + dd];
                    float b2 = XjL[(tj * 4 + 2) * 33 + dd];
                    float b3 = XjL[(tj * 4 + 3) * 33 + dd];
                    float t0;
                    t0 = a0 - b0; f[0][0] = fmaf(t0, t0, f[0][0]);
                    t0 = a0 - b1; f[0][1] = fmaf(t0, t0, f[0][1]);
                    t0 = a0 - b2; f[0][2] = fmaf(t0, t0, f[0][2]);
                    t0 = a0 - b3; f[0][3] = fmaf(t0, t0, f[0][3]);
                    t0 = a1 - b0; f[1][0] = fmaf(t0, t0, f[1][0]);
                    t0 = a1 - b1; f[1][1] = fmaf(t0, t0, f[1][1]);
                    t0 = a1 - b2; f[1][2] = fmaf(t0, t0, f[1][2]);
                    t0 = a1 - b3; f[1][3] = fmaf(t0, t0, f[1][3]);
                    t0 = a2 - b0; f[2][0] = fmaf(t0, t0, f[2][0]);
                    t0 = a2 - b1; f[2][1] = fmaf(t0, t0, f[2][1]);
                    t0 = a2 - b2; f[2][2] = fmaf(t0, t0, f[2][2]);
                    t0 = a2 - b3; f[2][3] = fmaf(t0, t0, f[2][3]);
                    t0 = a3 - b0; f[3][0] = fmaf(t0, t0, f[3][0]);
                    t0 = a3 - b1; f[3][1] = fmaf(t0, t0, f[3][1]);
                    t0 = a3 - b2; f[3][2] = fmaf(t0, t0, f[3][2]);
                    t0 = a3 - b3; f[3][3] = fmaf(t0, t0, f[3][3]);
                }
                int ib = i0 + ti * 4, jb = j0 + tj * 4;
                float lp = 0.f;
                #pragma unroll
                for (int r = 0; r < 4; r++) {
                    #pragma unroll
                    for (int c = 0; c < 4; c++) {
                        if (ib + r < m_i && jb + c < m_j) {
                            float dist = sqrtf(f[r][c]);
                            lp += __expf(bl[ti * 4 + r] + gl[tj * 4 + c] - dist);
                        }
                    }
                }
                part -= lp;                    // pairwise term is subtracted
            } else {
                int e = (task - npair) * NTHR + tid;
                if (e < E) {
                    int a = sei[e], b = sej[e];
                    const float4* xa = (const float4*)(Xi_all + (size_t)a * 32);
                    const float4* xb = (const float4*)(Xj_all + (size_t)b * 32);
                    float s = 0.f;
                    #pragma unroll
                    for (int qq = 0; qq < 8; qq++) {
                        float4 va = xa[qq], vb = xb[qq];
                        float t0;
                        t0 = va.x - vb.x + EPSC; s = fmaf(t0, t0, s);
                        t0 = va.y - vb.y + EPSC; s = fmaf(t0, t0, s);
                        t0 = va.z - vb.z + EPSC; s = fmaf(t0, t0, s);
                        t0 = va.w - vb.w + EPSC; s = fmaf(t0, t0, s);
                    }
                    part += beta[a] + gamma[b] - sqrtf(s);
                }
            }
        }
        __syncthreads();
        #pragma unroll
        for (int o = 32; o > 0; o >>= 1) part += __shfl_down(part, o, 64);
        if ((tid & 63) == 0) wsum[tid >> 6] = part;
        __syncthreads();
        if (tid == 0) {
            slots[bid] = wsum[0] + wsum[1] + wsum[2] + wsum[3];
            __threadfence();
            int ticket = atomicAdd(&cnt[2], 1);
            lastFlag[0] = (ticket == NBLK - 1) ? 1 : 0;
        }
        __syncthreads();
        if (lastFlag[0]) {
            __threadfence();
            float fv = 0.f;
            for (int i = tid; i < NBLK; i += NTHR)
                fv += __hip_atomic_load(&slots[i], __ATOMIC_RELAXED, __HIP_MEMORY_SCOPE_AGENT);
            #pragma unroll
            for (int o = 32; o > 0; o >>= 1) fv += __shfl_down(fv, o, 64);
            if ((tid & 63) == 0) wsum[tid >> 6] = fv;
            __syncthreads();
            if (tid == 0) out[0] = wsum[0] + wsum[1] + wsum[2] + wsum[3];
        }
    }
}

extern "C" void kernel_launch(void* const* d_in, const int* in_sizes, int n_in,
                              void* d_out, int out_size, void* d_ws, size_t ws_size,
                              hipStream_t stream) {
    const float* beta  = (const float*)d_in[0];
    const float* gamma = (const float*)d_in[1];
    const float* Amat  = (const float*)d_in[2];
    const float* Z_i   = (const float*)d_in[3];
    const float* Z_j   = (const float*)d_in[4];
    const float* Gate  = (const float*)d_in[5];
    const int*   si    = (const int*)d_in[6];
    const int*   sj    = (const int*)d_in[7];
    const int*   sei   = (const int*)d_in[8];
    const int*   sej   = (const int*)d_in[9];

    int n_i = in_sizes[0], n_j = in_sizes[1];
    int m_i = in_sizes[6], m_j = in_sizes[7], E = in_sizes[8];
    int m = m_i + m_j;

    float* ws = (float*)d_ws;
    float* Macc   = ws; ws += 1024;
    float* Sacc   = ws; ws += 32;
    int*   cnt    = (int*)ws; ws += 8;
    float* slots  = ws; ws += NBLK;
    float* Xi_all = ws; ws += (size_t)n_i * KDIM;
    float* Xj_all = ws; ws += (size_t)n_j * KDIM;

    // zero accumulators + barrier counters + slots (one small stream-ordered memset)
    (void)hipMemsetAsync(Macc, 0, (1024 + 32 + 8 + NBLK) * sizeof(float), stream);

    mega<<<NBLK, NTHR, 0, stream>>>(
        beta, gamma, Amat, Z_i, Z_j, Gate, si, sj, sei, sej,
        Macc, Sacc, cnt, slots, Xi_all, Xj_all,
        n_i, n_j, m_i, m_j, m, E, (float*)d_out);
}

// Round 7
// 98.759 us; speedup vs baseline: 3.8260x; 3.8260x over previous
//
#include <hip/hip_runtime.h>

#define KDIM 32
#define EPSC 1e-6f

// ============ K1: gather + inline softmax + M/S atomic reduction ============
// M[p][q] = sum_mi Zs[p][node_mi] * (Zs[q][node_mi] * sigmoid(Gate[node_mi][q]))
// s[q]    = sum_mi  Zs[q][node_mi] * sigmoid(Gate[node_mi][q])
__global__ __launch_bounds__(1024) void reduce_M(
    const float* __restrict__ Z_i, const float* __restrict__ Z_j,
    const float* __restrict__ Gate,
    const int* __restrict__ si, const int* __restrict__ sj,
    float* __restrict__ Macc, float* __restrict__ Sacc,
    int n_i, int n_j, int m_i, int m)
{
    __shared__ float Zl[32][33], Gl[32][33];
    __shared__ float cmax[32], cinv[32];
    __shared__ int nodeL[32];
    int q = threadIdx.x, p = threadIdx.y;
    int m0 = blockIdx.x * 32;
    if (p == 0) {
        int mi = m0 + q;
        nodeL[q] = (mi < m) ? ((mi < m_i) ? si[mi] : sj[mi - m_i]) : -1;
    }
    __syncthreads();
    int nq = nodeL[q];
    float zv = 0.f;
    if (nq >= 0) {
        int mi = m0 + q;
        const float* Zr = (mi < m_i) ? Z_i : Z_j;
        int n = (mi < m_i) ? n_i : n_j;
        zv = Zr[p * n + nq];
    }
    Zl[p][q] = zv;
    __syncthreads();
    if (p == 0) {   // per-column softmax stats
        float mx = -1e30f;
        #pragma unroll
        for (int r = 0; r < 32; r++) mx = fmaxf(mx, Zl[r][q]);
        float s = 0.f;
        #pragma unroll
        for (int r = 0; r < 32; r++) s += __expf(Zl[r][q] - mx);
        cmax[q] = mx; cinv[q] = 1.f / s;
    }
    __syncthreads();
    float zs = (nq >= 0) ? __expf(Zl[p][q] - cmax[q]) * cinv[q] : 0.f;
    Zl[p][q] = zs;          // own-cell overwrite, raw values consumed above
    __syncthreads();
    // Gl[p][q] = zsoft_sample_p[q] * sigmoid(Gate[node_p][q])  (raw node id — faithful)
    int np_ = nodeL[p];
    float gv = 0.f;
    if (np_ >= 0) {
        float g = 1.f / (1.f + __expf(-Gate[(size_t)np_ * KDIM + q]));
        gv = Zl[q][p] * g;
    }
    Gl[p][q] = gv;
    __syncthreads();
    float acc = 0.f;
    #pragma unroll
    for (int s = 0; s < 32; s++) acc = fmaf(Zl[p][s], Gl[s][q], acc);
    atomicAdd(&Macc[p * 32 + q], acc);
    if (p == 0) {
        float ss = 0.f;
        #pragma unroll
        for (int s = 0; s < 32; s++) ss += Gl[s][q];
        atomicAdd(&Sacc[q], ss);
    }
}

// ============ K2a: AZC = A @ (M / s)  (single tiny block, to global) ============
__global__ __launch_bounds__(1024) void azc_kernel(
    const float* __restrict__ Macc, const float* __restrict__ Sacc,
    const float* __restrict__ A, float* __restrict__ AZC)
{
    __shared__ float Cn[32][33];
    int q = threadIdx.x, p = threadIdx.y;
    Cn[p][q] = Macc[p * 32 + q] / Sacc[q];
    __syncthreads();
    float s = 0.f;
    #pragma unroll
    for (int j = 0; j < 32; j++) s = fmaf(A[p * 32 + j], Cn[j][q], s);
    AZC[p * 32 + q] = s;    // AZC[d=p][q]
}

// ============ K2b: X_all = (AZC @ softmax(Z)).T — AZC via uniform s_loads ============
__global__ __launch_bounds__(256) void xall(
    const float* __restrict__ AZC,
    const float* __restrict__ Z_i, const float* __restrict__ Z_j,
    float* __restrict__ Xi_all, float* __restrict__ Xj_all, int n_i, int n_j)
{
    int node = blockIdx.x * 256 + threadIdx.x;
    int nTot = n_i + n_j;
    if (node >= nTot) return;
    const float* Zr; float* X; int n, c;
    if (node < n_i) { Zr = Z_i; X = Xi_all; n = n_i; c = node; }
    else            { Zr = Z_j; X = Xj_all; n = n_j; c = node - n_i; }
    float z[32]; float mx = -1e30f;
    #pragma unroll
    for (int p = 0; p < 32; p++) { z[p] = Zr[p * n + c]; mx = fmaxf(mx, z[p]); }
    float ssum = 0.f;
    #pragma unroll
    for (int p = 0; p < 32; p++) { z[p] = __expf(z[p] - mx); ssum += z[p]; }
    float inv = 1.f / ssum;
    #pragma unroll
    for (int p = 0; p < 32; p++) z[p] *= inv;
    // AZC[dd*32+p] is wave-uniform -> scalar loads + SGPR-operand FMA
    #pragma unroll
    for (int d0 = 0; d0 < 8; d0++) {
        float xs[4];
        #pragma unroll
        for (int r = 0; r < 4; r++) {
            int dd = d0 * 4 + r;
            float x = 0.f;
            #pragma unroll
            for (int p = 0; p < 32; p++) x = fmaf(AZC[dd * 32 + p], z[p], x);
            xs[r] = x;
        }
        ((float4*)(X + (size_t)c * 32))[d0] = make_float4(xs[0], xs[1], xs[2], xs[3]);
    }
}

// ============ K3: pairwise tiles + edge blocks + ticket final ============
__global__ __launch_bounds__(256) void pair_edge_final(
    const float* __restrict__ Xi_all, const float* __restrict__ Xj_all,
    const int* __restrict__ si, const int* __restrict__ sj,
    const int* __restrict__ sei, const int* __restrict__ sej,
    const float* __restrict__ beta, const float* __restrict__ gamma,
    int m_i, int m_j, int E, int nbi, int nbj, int nblkTot,
    float* __restrict__ slots, int* __restrict__ cnt, float* __restrict__ out)
{
    __shared__ float XiL[64][33], XjL[64][33];
    __shared__ float bl[64], gl[64];
    __shared__ float wsum[4];
    __shared__ int lastFlag;
    int bid = blockIdx.x;
    int npair = nbi * nbj;
    int tid = threadIdx.x;
    float part = 0.f;

    if (bid < npair) {
        int i0 = (bid / nbj) * 64, j0 = (bid % nbj) * 64;
        #pragma unroll
        for (int l = 0; l < 8; l++) {
            int idx = tid + l * 256;
            int row = idx >> 5, dd = idx & 31;
            int gi = i0 + row;
            XiL[row][dd] = (gi < m_i) ? Xi_all[(size_t)si[gi] * 32 + dd] : 0.f;
            int gj = j0 + row;
            XjL[row][dd] = (gj < m_j) ? Xj_all[(size_t)sj[gj] * 32 + dd] : 0.f;
        }
        if (tid < 64) {
            bl[tid] = (i0 + tid < m_i) ? beta[si[i0 + tid]] : 0.f;
            gl[tid] = (j0 + tid < m_j) ? gamma[sj[j0 + tid]] : 0.f;
        }
        __syncthreads();
        int ti = tid >> 4, tj = tid & 15;
        float f[4][4] = {};
        #pragma unroll 4
        for (int dd = 0; dd < 32; dd++) {
            float a0 = XiL[ti * 4 + 0][dd] + EPSC;
            float a1 = XiL[ti * 4 + 1][dd] + EPSC;
            float a2 = XiL[ti * 4 + 2][dd] + EPSC;
            float a3 = XiL[ti * 4 + 3][dd] + EPSC;
            float b0 = XjL[tj * 4 + 0][dd];
            float b1 = XjL[tj * 4 + 1][dd];
            float b2 = XjL[tj * 4 + 2][dd];
            float b3 = XjL[tj * 4 + 3][dd];
            float t0;
            t0 = a0 - b0; f[0][0] = fmaf(t0, t0, f[0][0]);
            t0 = a0 - b1; f[0][1] = fmaf(t0, t0, f[0][1]);
            t0 = a0 - b2; f[0][2] = fmaf(t0, t0, f[0][2]);
            t0 = a0 - b3; f[0][3] = fmaf(t0, t0, f[0][3]);
            t0 = a1 - b0; f[1][0] = fmaf(t0, t0, f[1][0]);
            t0 = a1 - b1; f[1][1] = fmaf(t0, t0, f[1][1]);
            t0 = a1 - b2; f[1][2] = fmaf(t0, t0, f[1][2]);
            t0 = a1 - b3; f[1][3] = fmaf(t0, t0, f[1][3]);
            t0 = a2 - b0; f[2][0] = fmaf(t0, t0, f[2][0]);
            t0 = a2 - b1; f[2][1] = fmaf(t0, t0, f[2][1]);
            t0 = a2 - b2; f[2][2] = fmaf(t0, t0, f[2][2]);
            t0 = a2 - b3; f[2][3] = fmaf(t0, t0, f[2][3]);
            t0 = a3 - b0; f[3][0] = fmaf(t0, t0, f[3][0]);
            t0 = a3 - b1; f[3][1] = fmaf(t0, t0, f[3][1]);
            t0 = a3 - b2; f[3][2] = fmaf(t0, t0, f[3][2]);
            t0 = a3 - b3; f[3][3] = fmaf(t0, t0, f[3][3]);
        }
        int ib = i0 + ti * 4, jb = j0 + tj * 4;
        float lp = 0.f;
        #pragma unroll
        for (int r = 0; r < 4; r++) {
            #pragma unroll
            for (int c = 0; c < 4; c++) {
                if (ib + r < m_i && jb + c < m_j) {
                    float dist = sqrtf(f[r][c]);
                    lp += __expf(bl[ti * 4 + r] + gl[tj * 4 + c] - dist);
                }
            }
        }
        part = -lp;                     // pairwise term subtracted
    } else {
        int e = (bid - npair) * 256 + tid;
        if (e < E) {
            int a = sei[e], b = sej[e];
            const float4* xa = (const float4*)(Xi_all + (size_t)a * 32);
            const float4* xb = (const float4*)(Xj_all + (size_t)b * 32);
            float s = 0.f;
            #pragma unroll
            for (int qq = 0; qq < 8; qq++) {
                float4 va = xa[qq], vb = xb[qq];
                float t0;
                t0 = va.x - vb.x + EPSC; s = fmaf(t0, t0, s);
                t0 = va.y - vb.y + EPSC; s = fmaf(t0, t0, s);
                t0 = va.z - vb.z + EPSC; s = fmaf(t0, t0, s);
                t0 = va.w - vb.w + EPSC; s = fmaf(t0, t0, s);
            }
            part = beta[a] + gamma[b] - sqrtf(s);
        }
    }

    // block reduction -> slot -> ticket; last block reduces all slots
    #pragma unroll
    for (int o = 32; o > 0; o >>= 1) part += __shfl_down(part, o, 64);
    if ((tid & 63) == 0) wsum[tid >> 6] = part;
    __syncthreads();
    if (tid == 0) {
        float tot = wsum[0] + wsum[1] + wsum[2] + wsum[3];
        __hip_atomic_store(&slots[bid], tot, __ATOMIC_RELAXED, __HIP_MEMORY_SCOPE_AGENT);
        __threadfence();
        int ticket = atomicAdd(cnt, 1);
        lastFlag = (ticket == nblkTot - 1) ? 1 : 0;
    }
    __syncthreads();
    if (lastFlag) {
        __threadfence();
        float fv = 0.f;
        for (int i = tid; i < nblkTot; i += 256)
            fv += __hip_atomic_load(&slots[i], __ATOMIC_RELAXED, __HIP_MEMORY_SCOPE_AGENT);
        #pragma unroll
        for (int o = 32; o > 0; o >>= 1) fv += __shfl_down(fv, o, 64);
        if ((tid & 63) == 0) wsum[tid >> 6] = fv;
        __syncthreads();
        if (tid == 0) out[0] = wsum[0] + wsum[1] + wsum[2] + wsum[3];
    }
}

extern "C" void kernel_launch(void* const* d_in, const int* in_sizes, int n_in,
                              void* d_out, int out_size, void* d_ws, size_t ws_size,
                              hipStream_t stream) {
    const float* beta  = (const float*)d_in[0];
    const float* gamma = (const float*)d_in[1];
    const float* Amat  = (const float*)d_in[2];
    const float* Z_i   = (const float*)d_in[3];
    const float* Z_j   = (const float*)d_in[4];
    const float* Gate  = (const float*)d_in[5];
    const int*   si    = (const int*)d_in[6];
    const int*   sj    = (const int*)d_in[7];
    const int*   sei   = (const int*)d_in[8];
    const int*   sej   = (const int*)d_in[9];

    int n_i = in_sizes[0], n_j = in_sizes[1];
    int m_i = in_sizes[6], m_j = in_sizes[7], E = in_sizes[8];
    int m = m_i + m_j;
    int nTot = n_i + n_j;

    float* ws = (float*)d_ws;
    float* Macc   = ws; ws += 1024;
    float* Sacc   = ws; ws += 32;
    int*   cnt    = (int*)ws; ws += 8;
    float* AZC    = ws; ws += 1024;
    float* slots  = ws; ws += 4096;
    float* Xi_all = ws; ws += (size_t)n_i * KDIM;
    float* Xj_all = ws; ws += (size_t)n_j * KDIM;

    // zero Macc | Sacc | cnt (4256 B, stream-ordered, inside captured graph)
    (void)hipMemsetAsync(Macc, 0, (1024 + 32 + 8) * sizeof(float), stream);

    reduce_M<<<(m + 31) / 32, dim3(32, 32), 0, stream>>>(
        Z_i, Z_j, Gate, si, sj, Macc, Sacc, n_i, n_j, m_i, m);

    azc_kernel<<<1, dim3(32, 32), 0, stream>>>(Macc, Sacc, Amat, AZC);

    xall<<<(nTot + 255) / 256, 256, 0, stream>>>(AZC, Z_i, Z_j, Xi_all, Xj_all, n_i, n_j);

    int nbi = (m_i + 63) / 64, nbj = (m_j + 63) / 64;
    int nedge = (E + 255) / 256;
    int nblkTot = nbi * nbj + nedge;
    pair_edge_final<<<nblkTot, 256, 0, stream>>>(
        Xi_all, Xj_all, si, sj, sei, sej, beta, gamma,
        m_i, m_j, E, nbi, nbj, nblkTot, slots, cnt, (float*)d_out);
}

// Round 8
// 57.612 us; speedup vs baseline: 6.5585x; 1.7142x over previous
//
#include <hip/hip_runtime.h>

#define KDIM 32
#define EPSC 1e-6f
#define NEG_BIG (-1e30f)

// ============ K1: gather + inline softmax + M/S atomic reduction ============
__global__ __launch_bounds__(1024) void reduce_M(
    const float* __restrict__ Z_i, const float* __restrict__ Z_j,
    const float* __restrict__ Gate,
    const int* __restrict__ si, const int* __restrict__ sj,
    float* __restrict__ Macc, float* __restrict__ Sacc,
    int n_i, int n_j, int m_i, int m)
{
    __shared__ float Zl[32][33], Gl[32][33];
    __shared__ float cmax[32], cinv[32];
    __shared__ int nodeL[32];
    int q = threadIdx.x, p = threadIdx.y;
    int m0 = blockIdx.x * 32;
    if (p == 0) {
        int mi = m0 + q;
        nodeL[q] = (mi < m) ? ((mi < m_i) ? si[mi] : sj[mi - m_i]) : -1;
    }
    __syncthreads();
    int nq = nodeL[q];
    float zv = 0.f;
    if (nq >= 0) {
        int mi = m0 + q;
        const float* Zr = (mi < m_i) ? Z_i : Z_j;
        int n = (mi < m_i) ? n_i : n_j;
        zv = Zr[p * n + nq];
    }
    Zl[p][q] = zv;
    __syncthreads();
    if (p == 0) {
        float mx = -1e30f;
        #pragma unroll
        for (int r = 0; r < 32; r++) mx = fmaxf(mx, Zl[r][q]);
        float s = 0.f;
        #pragma unroll
        for (int r = 0; r < 32; r++) s += __expf(Zl[r][q] - mx);
        cmax[q] = mx; cinv[q] = 1.f / s;
    }
    __syncthreads();
    float zs = (nq >= 0) ? __expf(Zl[p][q] - cmax[q]) * cinv[q] : 0.f;
    Zl[p][q] = zs;
    __syncthreads();
    int np_ = nodeL[p];
    float gv = 0.f;
    if (np_ >= 0) {
        float g = 1.f / (1.f + __expf(-Gate[(size_t)np_ * KDIM + q]));
        gv = Zl[q][p] * g;   // raw node id for Gate — faithful to reference
    }
    Gl[p][q] = gv;
    __syncthreads();
    float acc = 0.f;
    #pragma unroll
    for (int s = 0; s < 32; s++) acc = fmaf(Zl[p][s], Gl[s][q], acc);
    atomicAdd(&Macc[p * 32 + q], acc);
    if (p == 0) {
        float ss = 0.f;
        #pragma unroll
        for (int s = 0; s < 32; s++) ss += Gl[s][q];
        atomicAdd(&Sacc[q], ss);
    }
}

// ============ K2a: AZC = A @ (M / s) ============
__global__ __launch_bounds__(1024) void azc_kernel(
    const float* __restrict__ Macc, const float* __restrict__ Sacc,
    const float* __restrict__ A, float* __restrict__ AZC)
{
    __shared__ float Cn[32][33];
    int q = threadIdx.x, p = threadIdx.y;
    Cn[p][q] = Macc[p * 32 + q] / Sacc[q];
    __syncthreads();
    float s = 0.f;
    #pragma unroll
    for (int j = 0; j < 32; j++) s = fmaf(A[p * 32 + j], Cn[j][q], s);
    AZC[p * 32 + q] = s;
}

// ============ K2b: X + norms; Xj stored pre-shifted by -EPSC ============
__global__ __launch_bounds__(256) void xall(
    const float* __restrict__ AZC,
    const float* __restrict__ Z_i, const float* __restrict__ Z_j,
    float* __restrict__ Xi_all, float* __restrict__ Xj_all,
    float* __restrict__ normI, float* __restrict__ normJ, int n_i, int n_j)
{
    int node = blockIdx.x * 256 + threadIdx.x;
    int nTot = n_i + n_j;
    if (node >= nTot) return;
    const float* Zr; float* X; float* Np; int n, c; float shift;
    if (node < n_i) { Zr = Z_i; X = Xi_all; Np = normI; n = n_i; c = node; shift = 0.f; }
    else            { Zr = Z_j; X = Xj_all; Np = normJ; n = n_j; c = node - n_i; shift = EPSC; }
    float z[32]; float mx = -1e30f;
    #pragma unroll
    for (int p = 0; p < 32; p++) { z[p] = Zr[p * n + c]; mx = fmaxf(mx, z[p]); }
    float ssum = 0.f;
    #pragma unroll
    for (int p = 0; p < 32; p++) { z[p] = __expf(z[p] - mx); ssum += z[p]; }
    float inv = 1.f / ssum;
    #pragma unroll
    for (int p = 0; p < 32; p++) z[p] *= inv;
    float nrm = 0.f;
    #pragma unroll
    for (int d0 = 0; d0 < 8; d0++) {
        float xs[4];
        #pragma unroll
        for (int r = 0; r < 4; r++) {
            int dd = d0 * 4 + r;
            float x = 0.f;
            #pragma unroll
            for (int p = 0; p < 32; p++) x = fmaf(AZC[dd * 32 + p], z[p], x);
            x -= shift;                 // y_j = x_j - eps; x_i unchanged
            nrm = fmaf(x, x, nrm);
            xs[r] = x;
        }
        ((float4*)(X + (size_t)c * 32))[d0] = make_float4(xs[0], xs[1], xs[2], xs[3]);
    }
    Np[c] = nrm;
}

// ============ K3: pairwise (Gram 128x128, 8x8/thread) + edge blocks ============
__global__ __launch_bounds__(256) void pair_edge(
    const float* __restrict__ Xi_all, const float* __restrict__ Xj_all,
    const float* __restrict__ normI, const float* __restrict__ normJ,
    const int* __restrict__ si, const int* __restrict__ sj,
    const int* __restrict__ sei, const int* __restrict__ sej,
    const float* __restrict__ beta, const float* __restrict__ gamma,
    int m_i, int m_j, int E, int nbi, int nbj, float* __restrict__ slots)
{
    __shared__ float XiL[128][36], XjL[128][36];   // 36: 144B rows, 16B-aligned
    __shared__ float an[128], bn[128], bel[128], gal[128];
    __shared__ float wsum[4];
    int bid = blockIdx.x, tid = threadIdx.x;
    int npair = nbi * nbj;
    float part = 0.f;

    if (bid < npair) {
        int i0 = (bid / nbj) * 128, j0 = (bid % nbj) * 128;
        if (tid < 128) {
            int gi = i0 + tid;
            if (gi < m_i) { int nd = si[gi]; an[tid] = normI[nd]; bel[tid] = beta[nd]; }
            else          { an[tid] = 0.f;  bel[tid] = NEG_BIG; }
        } else {
            int r = tid - 128, gj = j0 + r;
            if (gj < m_j) { int nd = sj[gj]; bn[r] = normJ[nd]; gal[r] = gamma[nd]; }
            else          { bn[r] = 0.f;  gal[r] = NEG_BIG; }
        }
        #pragma unroll
        for (int l = 0; l < 4; l++) {
            int slot = tid + l * 256;
            int row = slot >> 3, d4 = slot & 7;
            int gi = i0 + row;
            float4 v = make_float4(0.f, 0.f, 0.f, 0.f);
            if (gi < m_i) v = ((const float4*)(Xi_all + (size_t)si[gi] * 32))[d4];
            *(float4*)&XiL[row][d4 * 4] = v;
            int gj = j0 + row;
            float4 w = make_float4(0.f, 0.f, 0.f, 0.f);
            if (gj < m_j) w = ((const float4*)(Xj_all + (size_t)sj[gj] * 32))[d4];
            *(float4*)&XjL[row][d4 * 4] = w;
        }
        __syncthreads();
        int ti = tid & 15, tj = tid >> 4;   // i-rows: ti+16r ; j-rows: tj+16c
        float dot[8][8] = {};
        #pragma unroll
        for (int d4 = 0; d4 < 8; d4++) {
            float4 av[8], bv[8];
            #pragma unroll
            for (int r = 0; r < 8; r++) av[r] = *(const float4*)&XiL[ti + 16 * r][d4 * 4];
            #pragma unroll
            for (int c = 0; c < 8; c++) bv[c] = *(const float4*)&XjL[tj + 16 * c][d4 * 4];
            #pragma unroll
            for (int r = 0; r < 8; r++) {
                #pragma unroll
                for (int c = 0; c < 8; c++) {
                    dot[r][c] = fmaf(av[r].x, bv[c].x, dot[r][c]);
                    dot[r][c] = fmaf(av[r].y, bv[c].y, dot[r][c]);
                    dot[r][c] = fmaf(av[r].z, bv[c].z, dot[r][c]);
                    dot[r][c] = fmaf(av[r].w, bv[c].w, dot[r][c]);
                }
            }
        }
        float lp = 0.f;
        #pragma unroll
        for (int r = 0; r < 8; r++) {
            float ar = an[ti + 16 * r], br = bel[ti + 16 * r];
            #pragma unroll
            for (int c = 0; c < 8; c++) {
                float d2 = ar + bn[tj + 16 * c] - 2.f * dot[r][c];
                float dist = sqrtf(fmaxf(d2, 0.f));
                lp += __expf(br + gal[tj + 16 * c] - dist);
            }
        }
        part = -lp;
    } else {
        int e = (bid - npair) * 256 + tid;
        if (e < E) {
            int a = sei[e], b = sej[e];
            const float4* xa = (const float4*)(Xi_all + (size_t)a * 32);
            const float4* xb = (const float4*)(Xj_all + (size_t)b * 32);  // pre-shifted
            float s = 0.f;
            #pragma unroll
            for (int qq = 0; qq < 8; qq++) {
                float4 va = xa[qq], vb = xb[qq];
                float t0;
                t0 = va.x - vb.x; s = fmaf(t0, t0, s);
                t0 = va.y - vb.y; s = fmaf(t0, t0, s);
                t0 = va.z - vb.z; s = fmaf(t0, t0, s);
                t0 = va.w - vb.w; s = fmaf(t0, t0, s);
            }
            part = beta[a] + gamma[b] - sqrtf(s);
        }
    }

    // block reduce -> plain store (no atomics)
    #pragma unroll
    for (int o = 32; o > 0; o >>= 1) part += __shfl_down(part, o, 64);
    if ((tid & 63) == 0) wsum[tid >> 6] = part;
    __syncthreads();
    if (tid == 0) slots[bid] = wsum[0] + wsum[1] + wsum[2] + wsum[3];
}

// ============ K4: final reduce ============
__global__ __launch_bounds__(256) void final_reduce(
    const float* __restrict__ slots, int n, float* __restrict__ out)
{
    __shared__ float w[4];
    int tid = threadIdx.x;
    float v = 0.f;
    for (int i = tid; i < n; i += 256) v += slots[i];
    #pragma unroll
    for (int o = 32; o > 0; o >>= 1) v += __shfl_down(v, o, 64);
    if ((tid & 63) == 0) w[tid >> 6] = v;
    __syncthreads();
    if (tid == 0) out[0] = w[0] + w[1] + w[2] + w[3];
}

extern "C" void kernel_launch(void* const* d_in, const int* in_sizes, int n_in,
                              void* d_out, int out_size, void* d_ws, size_t ws_size,
                              hipStream_t stream) {
    const float* beta  = (const float*)d_in[0];
    const float* gamma = (const float*)d_in[1];
    const float* Amat  = (const float*)d_in[2];
    const float* Z_i   = (const float*)d_in[3];
    const float* Z_j   = (const float*)d_in[4];
    const float* Gate  = (const float*)d_in[5];
    const int*   si    = (const int*)d_in[6];
    const int*   sj    = (const int*)d_in[7];
    const int*   sei   = (const int*)d_in[8];
    const int*   sej   = (const int*)d_in[9];

    int n_i = in_sizes[0], n_j = in_sizes[1];
    int m_i = in_sizes[6], m_j = in_sizes[7], E = in_sizes[8];
    int m = m_i + m_j;
    int nTot = n_i + n_j;

    float* ws = (float*)d_ws;
    float* Macc   = ws; ws += 1024;
    float* Sacc   = ws; ws += 32;
    float* AZC    = ws; ws += 1024;
    float* slots  = ws; ws += 4096;
    float* normI  = ws; ws += n_i;
    float* normJ  = ws; ws += n_j;
    float* Xi_all = ws; ws += (size_t)n_i * KDIM;
    float* Xj_all = ws; ws += (size_t)n_j * KDIM;

    (void)hipMemsetAsync(Macc, 0, (1024 + 32) * sizeof(float), stream);

    reduce_M<<<(m + 31) / 32, dim3(32, 32), 0, stream>>>(
        Z_i, Z_j, Gate, si, sj, Macc, Sacc, n_i, n_j, m_i, m);

    azc_kernel<<<1, dim3(32, 32), 0, stream>>>(Macc, Sacc, Amat, AZC);

    xall<<<(nTot + 255) / 256, 256, 0, stream>>>(AZC, Z_i, Z_j, Xi_all, Xj_all,
                                                 normI, normJ, n_i, n_j);

    int nbi = (m_i + 127) / 128, nbj = (m_j + 127) / 128;
    int nedge = (E + 255) / 256;
    int nblkTot = nbi * nbj + nedge;
    pair_edge<<<nblkTot, 256, 0, stream>>>(
        Xi_all, Xj_all, normI, normJ, si, sj, sei, sej, beta, gamma,
        m_i, m_j, E, nbi, nbj, slots);

    final_reduce<<<1, 256, 0, stream>>>(slots, nblkTot, (float*)d_out);
}

// Round 9
// 54.087 us; speedup vs baseline: 6.9861x; 1.0652x over previous
//
#include <hip/hip_runtime.h>

#define KDIM 32
#define EPSC 1e-6f
#define NEG_BIG (-1e30f)
#define NGRP 16

// ============ K1: gather + inline softmax -> per-block partial M/S (no atomics) ============
__global__ __launch_bounds__(1024) void reduce_M(
    const float* __restrict__ Z_i, const float* __restrict__ Z_j,
    const float* __restrict__ Gate,
    const int* __restrict__ si, const int* __restrict__ sj,
    float* __restrict__ Mpart, float* __restrict__ Spart,
    int n_i, int n_j, int m_i, int m)
{
    __shared__ float Zl[32][33], Gl[32][33];
    __shared__ float cmax[32], cinv[32];
    __shared__ int nodeL[32];
    int q = threadIdx.x, p = threadIdx.y;
    int m0 = blockIdx.x * 32;
    if (p == 0) {
        int mi = m0 + q;
        nodeL[q] = (mi < m) ? ((mi < m_i) ? si[mi] : sj[mi - m_i]) : -1;
    }
    __syncthreads();
    int nq = nodeL[q];
    float zv = 0.f;
    if (nq >= 0) {
        int mi = m0 + q;
        const float* Zr = (mi < m_i) ? Z_i : Z_j;
        int n = (mi < m_i) ? n_i : n_j;
        zv = Zr[p * n + nq];
    }
    Zl[p][q] = zv;
    __syncthreads();
    if (p == 0) {
        float mx = -1e30f;
        #pragma unroll
        for (int r = 0; r < 32; r++) mx = fmaxf(mx, Zl[r][q]);
        float s = 0.f;
        #pragma unroll
        for (int r = 0; r < 32; r++) s += __expf(Zl[r][q] - mx);
        cmax[q] = mx; cinv[q] = 1.f / s;
    }
    __syncthreads();
    float zs = (nq >= 0) ? __expf(Zl[p][q] - cmax[q]) * cinv[q] : 0.f;
    Zl[p][q] = zs;          // own-cell overwrite; raw values consumed above
    __syncthreads();
    int np_ = nodeL[p];
    float gv = 0.f;
    if (np_ >= 0) {
        float g = 1.f / (1.f + __expf(-Gate[(size_t)np_ * KDIM + q]));
        gv = Zl[q][p] * g;   // raw node id for Gate — faithful to reference
    }
    Gl[p][q] = gv;
    __syncthreads();
    float acc = 0.f;
    #pragma unroll
    for (int s = 0; s < 32; s++) acc = fmaf(Zl[p][s], Gl[s][q], acc);
    Mpart[(size_t)blockIdx.x * 1024 + p * 32 + q] = acc;
    if (p == 0) {
        float ss = 0.f;
        #pragma unroll
        for (int s = 0; s < 32; s++) ss += Gl[s][q];
        Spart[(size_t)blockIdx.x * 32 + q] = ss;
    }
}

// ============ K1b: tree-reduce 157 partials -> 16 partials (coalesced, parallel) ============
__global__ __launch_bounds__(1024) void reduce2(
    const float* __restrict__ Mpart, const float* __restrict__ Spart, int nblkA,
    float* __restrict__ Mpart2, float* __restrict__ Spart2)
{
    int g = blockIdx.x;           // 0..NGRP-1
    int idx = threadIdx.x;        // 0..1023
    float s = 0.f;
    for (int b = g; b < nblkA; b += NGRP)
        s += Mpart[(size_t)b * 1024 + idx];
    Mpart2[g * 1024 + idx] = s;
    if (idx < 32) {
        float ss = 0.f;
        for (int b = g; b < nblkA; b += NGRP)
            ss += Spart[(size_t)b * 32 + idx];
        Spart2[g * 32 + idx] = ss;
    }
}

// ============ K2a: AZC = A @ (M / s) ============
__global__ __launch_bounds__(1024) void azc_kernel(
    const float* __restrict__ Mpart2, const float* __restrict__ Spart2,
    const float* __restrict__ A, float* __restrict__ AZC)
{
    __shared__ float Cn[32][33];
    __shared__ float Ssum[32];
    int q = threadIdx.x, p = threadIdx.y;
    int idx = p * 32 + q;
    float macc = 0.f;
    #pragma unroll
    for (int g = 0; g < NGRP; g++) macc += Mpart2[g * 1024 + idx];
    if (p == 0) {
        float ss = 0.f;
        #pragma unroll
        for (int g = 0; g < NGRP; g++) ss += Spart2[g * 32 + q];
        Ssum[q] = 1.f / ss;
    }
    __syncthreads();
    Cn[p][q] = macc * Ssum[q];
    __syncthreads();
    float s = 0.f;
    #pragma unroll
    for (int j = 0; j < 32; j++) s = fmaf(A[p * 32 + j], Cn[j][q], s);
    AZC[p * 32 + q] = s;
}

// ============ K2b: X + norms; Xj stored pre-shifted by -EPSC ============
__global__ __launch_bounds__(256) void xall(
    const float* __restrict__ AZC,
    const float* __restrict__ Z_i, const float* __restrict__ Z_j,
    float* __restrict__ Xi_all, float* __restrict__ Xj_all,
    float* __restrict__ normI, float* __restrict__ normJ, int n_i, int n_j)
{
    int node = blockIdx.x * 256 + threadIdx.x;
    int nTot = n_i + n_j;
    if (node >= nTot) return;
    const float* Zr; float* X; float* Np; int n, c; float shift;
    if (node < n_i) { Zr = Z_i; X = Xi_all; Np = normI; n = n_i; c = node; shift = 0.f; }
    else            { Zr = Z_j; X = Xj_all; Np = normJ; n = n_j; c = node - n_i; shift = EPSC; }
    float z[32]; float mx = -1e30f;
    #pragma unroll
    for (int p = 0; p < 32; p++) { z[p] = Zr[p * n + c]; mx = fmaxf(mx, z[p]); }
    float ssum = 0.f;
    #pragma unroll
    for (int p = 0; p < 32; p++) { z[p] = __expf(z[p] - mx); ssum += z[p]; }
    float inv = 1.f / ssum;
    #pragma unroll
    for (int p = 0; p < 32; p++) z[p] *= inv;
    float nrm = 0.f;
    #pragma unroll
    for (int d0 = 0; d0 < 8; d0++) {
        float xs[4];
        #pragma unroll
        for (int r = 0; r < 4; r++) {
            int dd = d0 * 4 + r;
            float x = 0.f;
            #pragma unroll
            for (int p = 0; p < 32; p++) x = fmaf(AZC[dd * 32 + p], z[p], x);
            x -= shift;                 // y_j = x_j - eps; x_i unchanged
            nrm = fmaf(x, x, nrm);
            xs[r] = x;
        }
        ((float4*)(X + (size_t)c * 32))[d0] = make_float4(xs[0], xs[1], xs[2], xs[3]);
    }
    Np[c] = nrm;
}

// ============ K3: pairwise (Gram 128x128, 8x8/thread) + edge blocks ============
__global__ __launch_bounds__(256) void pair_edge(
    const float* __restrict__ Xi_all, const float* __restrict__ Xj_all,
    const float* __restrict__ normI, const float* __restrict__ normJ,
    const int* __restrict__ si, const int* __restrict__ sj,
    const int* __restrict__ sei, const int* __restrict__ sej,
    const float* __restrict__ beta, const float* __restrict__ gamma,
    int m_i, int m_j, int E, int nbi, int nbj, float* __restrict__ slots)
{
    __shared__ float XiL[128][36], XjL[128][36];   // 36: 144B rows, 16B-aligned
    __shared__ float an[128], bn[128], bel[128], gal[128];
    __shared__ float wsum[4];
    int bid = blockIdx.x, tid = threadIdx.x;
    int npair = nbi * nbj;
    float part = 0.f;

    if (bid < npair) {
        int i0 = (bid / nbj) * 128, j0 = (bid % nbj) * 128;
        if (tid < 128) {
            int gi = i0 + tid;
            if (gi < m_i) { int nd = si[gi]; an[tid] = normI[nd]; bel[tid] = beta[nd]; }
            else          { an[tid] = 0.f;  bel[tid] = NEG_BIG; }
        } else {
            int r = tid - 128, gj = j0 + r;
            if (gj < m_j) { int nd = sj[gj]; bn[r] = normJ[nd]; gal[r] = gamma[nd]; }
            else          { bn[r] = 0.f;  gal[r] = NEG_BIG; }
        }
        #pragma unroll
        for (int l = 0; l < 4; l++) {
            int slot = tid + l * 256;
            int row = slot >> 3, d4 = slot & 7;
            int gi = i0 + row;
            float4 v = make_float4(0.f, 0.f, 0.f, 0.f);
            if (gi < m_i) v = ((const float4*)(Xi_all + (size_t)si[gi] * 32))[d4];
            *(float4*)&XiL[row][d4 * 4] = v;
            int gj = j0 + row;
            float4 w = make_float4(0.f, 0.f, 0.f, 0.f);
            if (gj < m_j) w = ((const float4*)(Xj_all + (size_t)sj[gj] * 32))[d4];
            *(float4*)&XjL[row][d4 * 4] = w;
        }
        __syncthreads();
        int ti = tid & 15, tj = tid >> 4;
        float dot[8][8] = {};
        #pragma unroll
        for (int d4 = 0; d4 < 8; d4++) {
            float4 av[8], bv[8];
            #pragma unroll
            for (int r = 0; r < 8; r++) av[r] = *(const float4*)&XiL[ti + 16 * r][d4 * 4];
            #pragma unroll
            for (int c = 0; c < 8; c++) bv[c] = *(const float4*)&XjL[tj + 16 * c][d4 * 4];
            #pragma unroll
            for (int r = 0; r < 8; r++) {
                #pragma unroll
                for (int c = 0; c < 8; c++) {
                    dot[r][c] = fmaf(av[r].x, bv[c].x, dot[r][c]);
                    dot[r][c] = fmaf(av[r].y, bv[c].y, dot[r][c]);
                    dot[r][c] = fmaf(av[r].z, bv[c].z, dot[r][c]);
                    dot[r][c] = fmaf(av[r].w, bv[c].w, dot[r][c]);
                }
            }
        }
        float lp = 0.f;
        #pragma unroll
        for (int r = 0; r < 8; r++) {
            float ar = an[ti + 16 * r], br = bel[ti + 16 * r];
            #pragma unroll
            for (int c = 0; c < 8; c++) {
                float d2 = fmaf(-2.f, dot[r][c], ar + bn[tj + 16 * c]);
                float dist = sqrtf(fmaxf(d2, 0.f));
                lp += __expf(br + gal[tj + 16 * c] - dist);
            }
        }
        part = -lp;
    } else {
        int e = (bid - npair) * 256 + tid;
        if (e < E) {
            int a = sei[e], b = sej[e];
            const float4* xa = (const float4*)(Xi_all + (size_t)a * 32);
            const float4* xb = (const float4*)(Xj_all + (size_t)b * 32);  // pre-shifted
            float s = 0.f;
            #pragma unroll
            for (int qq = 0; qq < 8; qq++) {
                float4 va = xa[qq], vb = xb[qq];
                float t0;
                t0 = va.x - vb.x; s = fmaf(t0, t0, s);
                t0 = va.y - vb.y; s = fmaf(t0, t0, s);
                t0 = va.z - vb.z; s = fmaf(t0, t0, s);
                t0 = va.w - vb.w; s = fmaf(t0, t0, s);
            }
            part = beta[a] + gamma[b] - sqrtf(s);
        }
    }

    #pragma unroll
    for (int o = 32; o > 0; o >>= 1) part += __shfl_down(part, o, 64);
    if ((tid & 63) == 0) wsum[tid >> 6] = part;
    __syncthreads();
    if (tid == 0) slots[bid] = wsum[0] + wsum[1] + wsum[2] + wsum[3];
}

// ============ K4: final reduce ============
__global__ __launch_bounds__(256) void final_reduce(
    const float* __restrict__ slots, int n, float* __restrict__ out)
{
    __shared__ float w[4];
    int tid = threadIdx.x;
    float v = 0.f;
    for (int i = tid; i < n; i += 256) v += slots[i];
    #pragma unroll
    for (int o = 32; o > 0; o >>= 1) v += __shfl_down(v, o, 64);
    if ((tid & 63) == 0) w[tid >> 6] = v;
    __syncthreads();
    if (tid == 0) out[0] = w[0] + w[1] + w[2] + w[3];
}

extern "C" void kernel_launch(void* const* d_in, const int* in_sizes, int n_in,
                              void* d_out, int out_size, void* d_ws, size_t ws_size,
                              hipStream_t stream) {
    const float* beta  = (const float*)d_in[0];
    const float* gamma = (const float*)d_in[1];
    const float* Amat  = (const float*)d_in[2];
    const float* Z_i   = (const float*)d_in[3];
    const float* Z_j   = (const float*)d_in[4];
    const float* Gate  = (const float*)d_in[5];
    const int*   si    = (const int*)d_in[6];
    const int*   sj    = (const int*)d_in[7];
    const int*   sei   = (const int*)d_in[8];
    const int*   sej   = (const int*)d_in[9];

    int n_i = in_sizes[0], n_j = in_sizes[1];
    int m_i = in_sizes[6], m_j = in_sizes[7], E = in_sizes[8];
    int m = m_i + m_j;
    int nTot = n_i + n_j;
    int nblkA = (m + 31) / 32;

    float* ws = (float*)d_ws;
    float* Mpart  = ws; ws += (size_t)nblkA * 1024;
    float* Spart  = ws; ws += (size_t)nblkA * 32;
    float* Mpart2 = ws; ws += NGRP * 1024;
    float* Spart2 = ws; ws += NGRP * 32;
    float* AZC    = ws; ws += 1024;
    float* slots  = ws; ws += 4096;
    float* normI  = ws; ws += n_i;
    float* normJ  = ws; ws += n_j;
    float* Xi_all = ws; ws += (size_t)n_i * KDIM;
    float* Xj_all = ws; ws += (size_t)n_j * KDIM;

    reduce_M<<<nblkA, dim3(32, 32), 0, stream>>>(
        Z_i, Z_j, Gate, si, sj, Mpart, Spart, n_i, n_j, m_i, m);

    reduce2<<<NGRP, 1024, 0, stream>>>(Mpart, Spart, nblkA, Mpart2, Spart2);

    azc_kernel<<<1, dim3(32, 32), 0, stream>>>(Mpart2, Spart2, Amat, AZC);

    xall<<<(nTot + 255) / 256, 256, 0, stream>>>(AZC, Z_i, Z_j, Xi_all, Xj_all,
                                                 normI, normJ, n_i, n_j);

    int nbi = (m_i + 127) / 128, nbj = (m_j + 127) / 128;
    int nedge = (E + 255) / 256;
    int nblkTot = nbi * nbj + nedge;
    pair_edge<<<nblkTot, 256, 0, stream>>>(
        Xi_all, Xj_all, normI, normJ, si, sj, sei, sej, beta, gamma,
        m_i, m_j, E, nbi, nbj, slots);

    final_reduce<<<1, 256, 0, stream>>>(slots, nblkTot, (float*)d_out);
}